// Round 3
// baseline (1021.485 us; speedup 1.0000x reference)
//
#include <hip/hip_runtime.h>
#include <hip/hip_fp16.h>

typedef unsigned int u32;
typedef _Float16 h2f __attribute__((ext_vector_type(2)));

#define BB 128
#define TT 512
#define DD 64
#define NBL 32
#define GIN 2080

// DPP quad_perm controls: xor1=0xB1, xor2=0x4E, xor3=0x1B; half_mirror=0x141.
template <int CTRL>
__device__ __forceinline__ float dpp_mov_f(float x) {
  return __builtin_bit_cast(
      float, __builtin_amdgcn_update_dpp(0, __builtin_bit_cast(int, x), CTRL,
                                         0xF, 0xF, true));
}
template <int CTRL>
__device__ __forceinline__ float dpp_add_f(float x) {
  return x + dpp_mov_f<CTRL>(x);
}
// ds_swizzle xor-16 within 32-lane group
__device__ __forceinline__ float swz_add16(float x) {
  return x + __builtin_bit_cast(float, __builtin_amdgcn_ds_swizzle(
                                           __builtin_bit_cast(int, x), 0x401F));
}
// ds_swizzle xor-4 (lane ^ 4), within 32-lane group
__device__ __forceinline__ float swz4(float x) {
  return __builtin_bit_cast(float, __builtin_amdgcn_ds_swizzle(
                                       __builtin_bit_cast(int, x), 0x101F));
}
__device__ __forceinline__ float xorf(float a, u32 m) {
  return __builtin_bit_cast(float, __builtin_bit_cast(u32, a) ^ m);
}

// sign of e_i * e_j in Cl(4,1): 1 if negative
__device__ inline int gp_negbit(int i, int j) {
  int sw = 0;
#pragma unroll
  for (int b = 0; b < 5; ++b)
    if ((j >> b) & 1) sw += __popc(i >> (b + 1));
  return (sw ^ ((i & j) >> 4)) & 1;  // METRIC[4] = -1
}

__device__ inline float fdot2f(u32 a, u32 b, float acc) {
#if __has_builtin(__builtin_amdgcn_fdot2)
  return __builtin_amdgcn_fdot2(__builtin_bit_cast(h2f, a),
                                __builtin_bit_cast(h2f, b), acc, false);
#else
  h2f av = __builtin_bit_cast(h2f, a), bv = __builtin_bit_cast(h2f, b);
  return acc + (float)av.x * (float)bv.x + (float)av.y * (float)bv.y;
#endif
}

__device__ inline u32 pkf16(float a, float b) {
  return __builtin_bit_cast(u32, __builtin_amdgcn_cvt_pkrtz(a, b));
}

__global__ __launch_bounds__(512, 2) void versor_main(
    const int* __restrict__ x, const float* __restrict__ emb,
    const float* __restrict__ gate_w, const float* __restrict__ gate_b,
    float* __restrict__ ws_h) {
  __shared__ float rn[4][NBL];   // normalized emb rows (init-only, for rc)
  __shared__ float inv_lds[4];   // 1/(||emb_row|| + eps)
  __shared__ float rc[4][DD];    // r-part of gate, pre-dotted
  __shared__ __align__(16) u32 h16t[2][16][68];  // f16x2 h transposed [pair][d]

  const int b = blockIdx.x;
  const int tid = threadIdx.x;
  const int w = tid >> 6;       // wave 0..7
  const int l = tid & 63;       // lane
  const int rl = l >> 3;        // 0..7
  const int d = (w << 3) + rl;  // this lane's row
  const int c = l & 7;          // GP owner quad / base blade
  const int r2g = l >> 5;       // gate row-quad group within wave (0..1)
  const int s = l & 31;         // gate 32-dword column slice

  // ---- init: normalized embeddings + inverse norms ----
  if (tid < 4) {
    float v[NBL];
    float sum = 0.f;
    for (int i = 0; i < NBL; ++i) {
      v[i] = emb[tid * NBL + i];
      sum += v[i] * v[i];
    }
    float sc = 1.f / (sqrtf(sum) + 1e-8f);
    inv_lds[tid] = sc;
    for (int i = 0; i < NBL; ++i) rn[tid][i] = v[i] * sc;
  }
  for (int idx = tid; idx < 16 * 68; idx += 512) {
    int m = idx / 68, dd = idx - m * 68;
    h16t[0][m][dd] = (m == 0 && dd < 64) ? 0x00003C00u : 0u;  // pack(1.0h,0)
  }
  __syncthreads();

  // ---- rc[e][row] = sum_i gate_w[row][2048+i] * rn[e][i] ----
  if (tid < 256) {
    int e = tid >> 6, row = tid & 63;
    float sum = 0.f;
    for (int i = 0; i < NBL; ++i) sum += gate_w[row * GIN + 2048 + i] * rn[e][i];
    rc[e][row] = sum;
  }

  // ---- gate weights -> registers (f16x2), 4 rows x 32 dwords per lane ----
  u32 gw[4][32];
#pragma unroll
  for (int rr = 0; rr < 4; ++rr) {
    const int row = (w << 3) + (r2g << 2) + rr;
    const float* wp = gate_w + row * GIN;
#pragma unroll
    for (int m = 0; m < 32; ++m) {
      int Dd = 32 * s + m;  // h16 dword index = pair*64 + d
      int pair = Dd >> 6, dd = Dd & 63;
      int col = dd * 32 + 2 * pair;
      gw[rr][m] = pkf16(wp[col], wp[col + 1]);
    }
  }
  const float gb = gate_b[d];

  // ---- per-lane sign masks for k=c (i-indexed) ----
  u32 sb[NBL];
#pragma unroll
  for (int i = 0; i < NBL; ++i) sb[i] = gp_negbit(i, i ^ c) ? 0x80000000u : 0u;
  __syncthreads();

  // per-lane copies of rc+gb and inv norms (select per step by xi, no LDS)
  float rcv[4], invv[4];
#pragma unroll
  for (int e = 0; e < 4; ++e) {
    rcv[e] = rc[e][d] + gb;
    invv[e] = inv_lds[e];
  }

  // ---- register-resident h state + butterfly neighborhood ----
  float u0 = (c == 0) ? 1.f : 0.f, u1 = 0.f, u2 = 0.f, u3 = 0.f;
  float4 hq[8];
  auto bfly = [&]() {
    hq[0] = make_float4(u0, u1, u2, u3);
    hq[1] = make_float4(dpp_mov_f<0xB1>(u0), dpp_mov_f<0xB1>(u1),
                        dpp_mov_f<0xB1>(u2), dpp_mov_f<0xB1>(u3));
    hq[2] = make_float4(dpp_mov_f<0x4E>(u0), dpp_mov_f<0x4E>(u1),
                        dpp_mov_f<0x4E>(u2), dpp_mov_f<0x4E>(u3));
    hq[3] = make_float4(dpp_mov_f<0x1B>(u0), dpp_mov_f<0x1B>(u1),
                        dpp_mov_f<0x1B>(u2), dpp_mov_f<0x1B>(u3));
    float s0 = swz4(u0), s1 = swz4(u1), s2 = swz4(u2), s3 = swz4(u3);
    hq[4] = make_float4(s0, s1, s2, s3);
    hq[5] = make_float4(dpp_mov_f<0xB1>(s0), dpp_mov_f<0xB1>(s1),
                        dpp_mov_f<0xB1>(s2), dpp_mov_f<0xB1>(s3));
    hq[6] = make_float4(dpp_mov_f<0x4E>(s0), dpp_mov_f<0x4E>(s1),
                        dpp_mov_f<0x4E>(s2), dpp_mov_f<0x4E>(s3));
    hq[7] = make_float4(dpp_mov_f<0x1B>(s0), dpp_mov_f<0x1B>(s1),
                        dpp_mov_f<0x1B>(s2), dpp_mov_f<0x1B>(s3));
  };
  bfly();

  auto step = [&](int p, int xi, const float (&rnr)[NBL]) {
    const int pn = p ^ 1;

    // ---- gate: 4 rows x 32 dwords of f16 dot2 (only remaining LDS read) ----
    const u32* Hb = &h16t[p][s >> 1][(s & 1) << 5];
    float a0 = 0.f, a1 = 0.f, a2 = 0.f, a3 = 0.f;
#pragma unroll
    for (int jq = 0; jq < 8; ++jq) {
      uint4 hv = *(const uint4*)(Hb + (jq << 2));
      a0 = fdot2f(gw[0][4 * jq + 0], hv.x, a0);
      a0 = fdot2f(gw[0][4 * jq + 1], hv.y, a0);
      a0 = fdot2f(gw[0][4 * jq + 2], hv.z, a0);
      a0 = fdot2f(gw[0][4 * jq + 3], hv.w, a0);
      a1 = fdot2f(gw[1][4 * jq + 0], hv.x, a1);
      a1 = fdot2f(gw[1][4 * jq + 1], hv.y, a1);
      a1 = fdot2f(gw[1][4 * jq + 2], hv.z, a1);
      a1 = fdot2f(gw[1][4 * jq + 3], hv.w, a1);
      a2 = fdot2f(gw[2][4 * jq + 0], hv.x, a2);
      a2 = fdot2f(gw[2][4 * jq + 1], hv.y, a2);
      a2 = fdot2f(gw[2][4 * jq + 2], hv.z, a2);
      a2 = fdot2f(gw[2][4 * jq + 3], hv.w, a2);
      a3 = fdot2f(gw[3][4 * jq + 0], hv.x, a3);
      a3 = fdot2f(gw[3][4 * jq + 1], hv.y, a3);
      a3 = fdot2f(gw[3][4 * jq + 2], hv.z, a3);
      a3 = fdot2f(gw[3][4 * jq + 3], hv.w, a3);
    }
    a0 = dpp_add_f<0xB1>(a0); a0 = dpp_add_f<0x4E>(a0);
    a0 = dpp_add_f<0x141>(a0); a0 = dpp_add_f<0x140>(a0); a0 = swz_add16(a0);
    a1 = dpp_add_f<0xB1>(a1); a1 = dpp_add_f<0x4E>(a1);
    a1 = dpp_add_f<0x141>(a1); a1 = dpp_add_f<0x140>(a1); a1 = swz_add16(a1);
    a2 = dpp_add_f<0xB1>(a2); a2 = dpp_add_f<0x4E>(a2);
    a2 = dpp_add_f<0x141>(a2); a2 = dpp_add_f<0x140>(a2); a2 = swz_add16(a2);
    a3 = dpp_add_f<0xB1>(a3); a3 = dpp_add_f<0x4E>(a3);
    a3 = dpp_add_f<0x141>(a3); a3 = dpp_add_f<0x140>(a3); a3 = swz_add16(a3);
    const int jsel = rl & 3;
    float zv = (jsel == 0) ? a0 : (jsel == 1) ? a1 : (jsel == 2) ? a2 : a3;
    float rcsel = (xi == 0) ? rcv[0] : (xi == 1) ? rcv[1]
                  : (xi == 2) ? rcv[2] : rcv[3];
    float invsel = (xi == 0) ? invv[0] : (xi == 1) ? invv[1]
                   : (xi == 2) ? invv[2] : invv[3];
    float zg = zv + rcsel;
    float g = 1.f / (1.f + exp2f(-1.44269504f * zg));

    // ---- geometric product from SGPR-resident raw emb row + register hq ----
    float b0 = 0.f, b1_ = 0.f, b2_ = 0.f, b3_ = 0.f;
#pragma unroll
    for (int q = 0; q < 8; ++q) {
      float t0 = xorf(rnr[q], sb[q]);
      float t1 = xorf(rnr[q + 8], sb[q + 8]);
      float t2 = xorf(rnr[q + 16], sb[q + 16]);
      float t3 = xorf(rnr[q + 24], sb[q + 24]);
      b0 = fmaf(t0, hq[q].x, b0);
      b1_ = fmaf(t0, hq[q].y, b1_);
      b2_ = fmaf(t0, hq[q].z, b2_);
      b3_ = fmaf(t0, hq[q].w, b3_);
      b0 = fmaf(t1, hq[q].y, b0);
      b1_ = fmaf(t1, hq[q].x, b1_);
      b2_ = fmaf(t1, hq[q].w, b2_);
      b3_ = fmaf(t1, hq[q].z, b3_);
      b0 = fmaf(t2, hq[q].z, b0);
      b1_ = fmaf(-t2, hq[q].w, b1_);
      b2_ = fmaf(-t2, hq[q].x, b2_);
      b3_ = fmaf(t2, hq[q].y, b3_);
      b0 = fmaf(t3, hq[q].w, b0);
      b1_ = fmaf(-t3, hq[q].z, b1_);
      b2_ = fmaf(-t3, hq[q].y, b2_);
      b3_ = fmaf(t3, hq[q].x, b3_);
    }

    // ---- gated update (norm folded post-dot) + mnorm over 8-lane group ----
    float gi = g * invsel;
    float om = 1.f - g;
    u0 = fmaf(gi, b0, om * hq[0].x);
    u1 = fmaf(gi, b1_, om * hq[0].y);
    u2 = fmaf(gi, b2_, om * hq[0].z);
    u3 = fmaf(gi, b3_, om * hq[0].w);
    float sq = u0 * u0 + u1 * u1 + u2 * u2 + u3 * u3;
    sq = dpp_add_f<0xB1>(sq);
    sq = dpp_add_f<0x4E>(sq);
    sq = dpp_add_f<0x141>(sq);
    float sc = 1.f / (sqrtf(sq) + 1e-8f);
    u0 *= sc; u1 *= sc; u2 *= sc; u3 *= sc;

    // f16x2 transposed copy for the gate (partner via DPP xor1)
    float v0 = dpp_mov_f<0xB1>(u0);
    float v1 = dpp_mov_f<0xB1>(u1);
    float v2 = dpp_mov_f<0xB1>(u2);
    float v3 = dpp_mov_f<0xB1>(u3);
    if (!(l & 1)) {  // even c packs (c, c+1)
      h16t[pn][(c) >> 1][d] = pkf16(u0, v0);
      h16t[pn][(c + 8) >> 1][d] = pkf16(u1, v1);
      h16t[pn][(c + 16) >> 1][d] = pkf16(u2, v2);
      h16t[pn][(c + 24) >> 1][d] = pkf16(u3, v3);
    }
    bfly();  // neighborhood for next step (registers only, no barrier dep)
    __syncthreads();
  };

  // ---- software-pipelined scalar loads of x / raw emb rows ----
  const int* xg = x + b * TT;
  int xiA = xg[0];
  int xiB = xg[1];
  float rnA[NBL], rnB[NBL];
#pragma unroll
  for (int i = 0; i < NBL; ++i) rnA[i] = emb[xiA * NBL + i];

  for (int t = 0; t < TT; t += 2) {
#pragma unroll
    for (int i = 0; i < NBL; ++i) rnB[i] = emb[xiB * NBL + i];
    int xiC = xg[(t + 2 < TT) ? t + 2 : 0];
    step(0, xiA, rnA);
#pragma unroll
    for (int i = 0; i < NBL; ++i) rnA[i] = emb[xiC * NBL + i];
    int xiD = xg[(t + 3 < TT) ? t + 3 : 0];
    step(1, xiB, rnB);
    xiA = xiC;
    xiB = xiD;
  }

  // final h: u regs hold h[d][c+8j], write blade-order to ws
  float* wo = ws_h + b * 2048 + d * 32 + c;
  wo[0] = u0;
  wo[8] = u1;
  wo[16] = u2;
  wo[24] = u3;
}

// 128 blocks x 256 threads, 2 lanes per output row
__global__ __launch_bounds__(256) void versor_head(
    const float* __restrict__ ws_h, const float* __restrict__ w1,
    const float* __restrict__ b1, const float* __restrict__ ln_g,
    const float* __restrict__ ln_b, const float* __restrict__ w2,
    const float* __restrict__ b2, float* __restrict__ out) {
  __shared__ __align__(16) float hs[2048];
  __shared__ float red[4][2];
  const int bctx = blockIdx.x, tid = threadIdx.x;
  {
    const float4* src = (const float4*)(ws_h + bctx * 2048);
    float4* dst = (float4*)hs;
    for (int i = tid; i < 512; i += 256) dst[i] = src[i];
  }
  __syncthreads();
  const int r = tid >> 1, half = tid & 1, wv = tid >> 6;
  float acc = half ? 0.f : b1[r];
  const float4* w4 = (const float4*)(w1 + r * 2048 + half * 1024);
  const float4* h4 = (const float4*)(hs + half * 1024);
#pragma unroll 8
  for (int k = 0; k < 256; ++k) {
    float4 a = w4[k], hv = h4[k];
    acc = fmaf(a.x, hv.x, acc);
    acc = fmaf(a.y, hv.y, acc);
    acc = fmaf(a.z, hv.z, acc);
    acc = fmaf(a.w, hv.w, acc);
  }
  acc += __shfl_xor(acc, 1, 64);  // both halves hold full row dot
  // LN stats: reduce over even-xor subgroup => each row counted once
  float s1 = acc, s2 = acc * acc;
#pragma unroll
  for (int off = 2; off <= 32; off <<= 1) {
    s1 += __shfl_xor(s1, off, 64);
    s2 += __shfl_xor(s2, off, 64);
  }
  if ((tid & 63) == 0) { red[wv][0] = s1; red[wv][1] = s2; }
  __syncthreads();
  float tot1 = red[0][0] + red[1][0] + red[2][0] + red[3][0];
  float tot2 = red[0][1] + red[1][1] + red[2][1] + red[3][1];
  float mu = tot1 * (1.f / 128.f);
  float var = tot2 * (1.f / 128.f) - mu * mu;
  float z = (acc - mu) * rsqrtf(var + 1e-5f) * ln_g[r] + ln_b[r];
  z = fmaxf(z, 0.f);
  __syncthreads();
  float p0 = z * w2[r], p1 = z * w2[128 + r];
#pragma unroll
  for (int off = 2; off <= 32; off <<= 1) {
    p0 += __shfl_xor(p0, off, 64);
    p1 += __shfl_xor(p1, off, 64);
  }
  if ((tid & 63) == 0) { red[wv][0] = p0; red[wv][1] = p1; }
  __syncthreads();
  if (tid == 0) {
    out[bctx * 2 + 0] = red[0][0] + red[1][0] + red[2][0] + red[3][0] + b2[0];
    out[bctx * 2 + 1] = red[0][1] + red[1][1] + red[2][1] + red[3][1] + b2[1];
  }
}

extern "C" void kernel_launch(void* const* d_in, const int* in_sizes, int n_in,
                              void* d_out, int out_size, void* d_ws,
                              size_t ws_size, hipStream_t stream) {
  (void)in_sizes; (void)n_in; (void)out_size; (void)ws_size;
  const int* x = (const int*)d_in[0];
  const float* emb = (const float*)d_in[1];
  const float* gate_w = (const float*)d_in[2];
  const float* gate_b = (const float*)d_in[3];
  const float* w1 = (const float*)d_in[4];
  const float* b1 = (const float*)d_in[5];
  const float* ln_g = (const float*)d_in[6];
  const float* ln_b = (const float*)d_in[7];
  const float* w2 = (const float*)d_in[8];
  const float* b2 = (const float*)d_in[9];
  float* out = (float*)d_out;
  float* ws_h = (float*)d_ws;  // 128*2048 floats = 1 MB

  versor_main<<<dim3(BB), dim3(512), 0, stream>>>(x, emb, gate_w, gate_b, ws_h);
  versor_head<<<dim3(BB), dim3(256), 0, stream>>>(ws_h, w1, b1, ln_g, ln_b, w2,
                                                  b2, out);
}